// Round 17
// baseline (724.348 us; speedup 1.0000x reference)
//
#include <hip/hip_runtime.h>
#include <hip/hip_bf16.h>

#define NTOT 3145728   // 256*3*64*64
#define NIMG 768       // 256*3
#define CTAPS 1024     // GL conv truncation
#define NBAND 66       // conv bands: d = -1 .. 64

typedef __attribute__((ext_vector_type(8)))  short bf16x8;
typedef __attribute__((ext_vector_type(4)))  short bf16x4;
typedef __attribute__((ext_vector_type(8)))  unsigned short u16x8;
typedef __attribute__((ext_vector_type(4)))  unsigned short u16x4;
typedef __attribute__((ext_vector_type(4)))  unsigned uint32x4;
typedef __attribute__((ext_vector_type(4)))  float f32x4;
typedef __attribute__((ext_vector_type(16))) float f32x16;

__device__ inline unsigned short f2bf(float x) {
    unsigned u = __builtin_bit_cast(unsigned, x);
    u += 0x7fffu + ((u >> 16) & 1u);
    return (unsigned short)(u >> 16);
}
__device__ inline float bf2f(unsigned short u) {
    return __builtin_bit_cast(float, (unsigned)u << 16);
}
__device__ inline void split2(float v, unsigned short& hi, unsigned short& lo) {
    hi = f2bf(v);
    lo = f2bf(v - bf2f(hi));
}
// HW packed RNE convert: low16 <- bf16(a), high16 <- bf16(b). Same RNE as f2bf.
__device__ inline unsigned cvt_pk_bf16(float a, float b) {
    unsigned r;
    asm("v_cvt_pk_bf16_f32 %0, %1, %2" : "=v"(r) : "v"(a), "v"(b));
    return r;
}
__device__ inline bf16x8 ld2(const unsigned short* p) {   // 8B-aligned LDS read
    bf16x4 a = *(const bf16x4*)p;
    bf16x4 b = *(const bf16x4*)(p + 4);
    bf16x8 r;
    #pragma unroll
    for (int i = 0; i < 4; ++i) { r[i] = a[i]; r[4 + i] = b[i]; }
    return r;
}

// ---------------------------------------------------------------- tables ----
__global__ __launch_bounds__(1024)
void gen_tables(unsigned short* __restrict__ Tch, unsigned short* __restrict__ Tsh,
                unsigned short* __restrict__ Bth, unsigned short* __restrict__ fph)
{
    __shared__ float wsm[CTAPS];
    const int tid = threadIdx.x;
    const int bid = blockIdx.x;
    const float step = 6.28318530717958647692f / 64.0f;
    if (tid < 512) {
        int i = bid * 512 + tid;
        int p = i >> 6, q = i & 63;
        float ang = (float)((p * q) & 63) * step;
        Tch[i] = f2bf(cosf(ang));
        Tsh[i] = f2bf(sinf(ang));
    }
    if (bid == 0) fph[tid] = 0;                // 1024-element zero prefix
    if (tid < 64) {
        const int l = tid;
        float vals[16];
        float local = 1.0f;
        #pragma unroll
        for (int m = 0; m < 16; ++m) {
            int j = 16 * l + 1 + m;
            local *= ((float)j - 1.5f) / (float)j;
            vals[m] = local;
        }
        float scan = local;
        #pragma unroll
        for (int d = 1; d < 64; d <<= 1) {
            float o = __shfl_up(scan, (unsigned)d, 64);
            if (l >= d) scan *= o;
        }
        float prefix = __shfl_up(scan, 1u, 64);
        if (l == 0) prefix = 1.0f;
        const float s = sqrtf((float)(NTOT - 1));
        if (l == 0) wsm[0] = s;
        #pragma unroll
        for (int m = 0; m < 16; ++m) {
            int j = 16 * l + 1 + m;
            if (j < CTAPS) wsm[j] = prefix * vals[m] * s;
        }
    }
    __syncthreads();
    const int i0 = bid * 4224;                 // 66*512/8 = 4224 per block
    for (int i = i0 + tid; i < i0 + 4224; i += 1024) {
        int d = (i >> 9) - 1, o = (i >> 4) & 31, u = i & 15;
        int j = 16 * d + o - u;
        Bth[i] = (j >= 0 && j < CTAPS) ? f2bf(wsm[j]) : (unsigned short)0;
    }
}

// ---------------------------------------------------------- MFMA 2-D DFT ---
template<int INV>
__global__ __launch_bounds__(256)
void dft_mfma(const void* __restrict__ Xin,
              const unsigned short* __restrict__ Tch, const unsigned short* __restrict__ Tsh,
              void* __restrict__ Out)
{
    __shared__ __align__(16) unsigned short Xh[64 * 68];
    __shared__ __align__(16) unsigned short Chh[64 * 68];
    __shared__ __align__(16) unsigned short Shh[64 * 68];
    const int tid = threadIdx.x;
    const int img = blockIdx.x;
    {
        const int rr = tid >> 2, c0 = (tid & 3) * 16;
        const int lb = rr * 68 + c0;
        if constexpr (!INV) {
            const float* Xf = (const float*)Xin + (size_t)img * 4096 + rr * 64 + c0;
            #pragma unroll
            for (int i = 0; i < 4; ++i) {
                float4 v = *(const float4*)(Xf + 4 * i);
                ushort4 u = {f2bf(v.x), f2bf(v.y), f2bf(v.z), f2bf(v.w)};
                *(ushort4*)&Xh[lb + 4 * i] = u;
            }
        } else {
            const unsigned short* Ph = (const unsigned short*)Xin + (size_t)img * 4096 + rr * 64 + c0;
            #pragma unroll
            for (int i = 0; i < 4; ++i)
                *(ushort4*)&Xh[lb + 4 * i] = *(const ushort4*)(Ph + 4 * i);
        }
    }
    __syncthreads();

    const int lane = tid & 63, wv = tid >> 6;
    const int r = lane & 31, g = lane >> 5;
    const int q0 = (wv >> 1) * 32, r0 = (wv & 1) * 32;
    const int tA = (q0 + r) * 64;     // T row base (A operand)
    const int xB = (r0 + r) * 68;     // X / C / S row base (B operand)

    f32x16 a1, b1;
    #pragma unroll
    for (int i = 0; i < 16; ++i) { a1[i] = 0.f; b1[i] = 0.f; }
    #pragma unroll
    for (int ks = 0; ks < 4; ++ks) {
        const int ko = ks * 16 + 8 * g;
        bf16x8 xh = ld2(&Xh[xB + ko]);
        bf16x8 tc = *(const bf16x8*)&Tch[tA + ko];
        bf16x8 ts = *(const bf16x8*)&Tsh[tA + ko];
        a1 = __builtin_amdgcn_mfma_f32_32x32x16_bf16(tc, xh, a1, 0, 0, 0);
        b1 = __builtin_amdgcn_mfma_f32_32x32x16_bf16(ts, xh, b1, 0, 0, 0);
    }
    #pragma unroll
    for (int reg = 0; reg < 16; ++reg) {
        int qq = q0 + (reg & 3) + 8 * (reg >> 2) + 4 * g;
        Chh[qq * 68 + r0 + r] = f2bf(a1[reg]);
        Shh[qq * 68 + r0 + r] = f2bf(-b1[reg]);
    }
    __syncthreads();

    #pragma unroll
    for (int i = 0; i < 16; ++i) a1[i] = 0.f;
    #pragma unroll
    for (int ks = 0; ks < 4; ++ks) {
        const int ko = ks * 16 + 8 * g;
        bf16x8 ch = ld2(&Chh[xB + ko]);
        bf16x8 tc = *(const bf16x8*)&Tch[tA + ko];
        a1 = __builtin_amdgcn_mfma_f32_32x32x16_bf16(tc, ch, a1, 0, 0, 0);
        bf16x8 sh = ld2(&Shh[xB + ko]);
        bf16x8 ts = *(const bf16x8*)&Tsh[tA + ko];
        a1 = __builtin_amdgcn_mfma_f32_32x32x16_bf16(ts, sh, a1, 0, 0, 0);
    }
    #pragma unroll
    for (int reg = 0; reg < 16; ++reg) {
        int pp = q0 + (reg & 3) + 8 * (reg >> 2) + 4 * g;
        size_t oi = (size_t)img * 4096 + (size_t)pp * 64 + r0 + r;
        if constexpr (INV)
            ((float*)Out)[oi] = a1[reg] * (1.0f / 4096.0f);
        else
            ((unsigned short*)Out)[oi] = f2bf(a1[reg]);
    }
}

// ----------------------------------------------------------- MFMA conv -----
__global__ __launch_bounds__(256)
void conv_mfma(const unsigned short* __restrict__ fh,
               const unsigned short* __restrict__ Bth,
               unsigned short* __restrict__ fr)
{
    __shared__ __align__(16) unsigned short Ah[5120];
    const int tid = threadIdx.x;
    const size_t tb0 = (size_t)blockIdx.x * 4096;
    {
        const unsigned short* sh = fh + tb0 - 1024;   // zero prefix covers block 0
        for (int gg = tid; gg < 640; gg += 256) {
            int off = (gg ^ ((gg >> 3) & 7)) << 3;    // swizzled element offset
            *(bf16x8*)&Ah[off] = *(const bf16x8*)(sh + gg * 8);
        }
    }
    __syncthreads();

    const int lane = tid & 63;
    const int wv = tid >> 6;
    const int r = lane & 31, g = lane >> 5;
    const int bo = 16 * r + 8 * g;
    const int base_gg = 128 * (wv + 1) + 4 * r + g + 2;   // A-frag group at dd=0

    f32x16 a1;
    #pragma unroll
    for (int i = 0; i < 16; ++i) a1[i] = 0.f;

    const unsigned short* bhp = Bth + bo;
    bf16x8 bh0 = *(const bf16x8*)(bhp);
    bf16x8 bh1 = *(const bf16x8*)(bhp + 512);

    for (int dd = 0; dd < NBAND; dd += 2) {
        bf16x8 nh0, nh1;
        if (dd + 2 < NBAND) {
            nh0 = *(const bf16x8*)(bhp + 512 * (dd + 2));
            nh1 = *(const bf16x8*)(bhp + 512 * (dd + 3));
        }
        {
            int gg = base_gg - 2 * dd;
            int off = (gg ^ ((gg >> 3) & 7)) << 3;
            bf16x8 avh = *(const bf16x8*)&Ah[off];
            a1 = __builtin_amdgcn_mfma_f32_32x32x16_bf16(avh, bh0, a1, 0, 0, 0);
        }
        {
            int gg = base_gg - 2 * (dd + 1);
            int off = (gg ^ ((gg >> 3) & 7)) << 3;
            bf16x8 avh = *(const bf16x8*)&Ah[off];
            a1 = __builtin_amdgcn_mfma_f32_32x32x16_bf16(avh, bh1, a1, 0, 0, 0);
        }
        bh0 = nh0; bh1 = nh1;
    }

    const size_t tb = tb0 + 1024 * wv;
    #pragma unroll
    for (int reg = 0; reg < 16; ++reg) {
        int row = (reg & 3) + 8 * (reg >> 2) + 4 * g;
        fr[tb + 32 * row + r] = f2bf(a1[reg]);
    }
}

// ----------------------------------------------------- dense-stack device ---
// gemm: D = A(bf16) @ W(f32 direct, cvt_pk in-register). 128x64 tile, 4
// waves, BK=32, no LDS, no in-loop barriers, 2-deep named-register prefetch.
template<int MODE, int RELU, int XMAP>
__device__ void gemm_dev(const unsigned short* __restrict__ A, const float* __restrict__ W,
                         void* __restrict__ Out, const float* __restrict__ bias,
                         int M, int N, int K, int kChunk, int nbn, int nz, int id)
{
    const int tid = threadIdx.x;
    int bm, bn, z;
    if (XMAP == 0) {
        const int gq = id >> 4, rr = id & 15;      // GRP = 16
        const int t  = gq * 8 + (rr & 7);
        bm = (rr >> 3) * 128;
        bn = (t % nbn) * 64;
        z  = t / nbn;
    } else {
        const int x = id & 7, j = id >> 3;
        const int p = x + 8 * (j / nbn);           // (bm,z) pair, pinned to XCD x
        bn = (j % nbn) * 64;
        bm = (p / nz) * 128;
        z  = p % nz;
    }
    const int kb0 = z * kChunk;
    const int nsteps = kChunk >> 5;            // must be EVEN

    const int lane = tid & 63, wv = tid >> 6;
    const int wr = (wv >> 1) * 64, wc = (wv & 1) * 32;
    const int l15 = lane & 15, l4 = lane >> 4;

    f32x4 acc[4][2];
    #pragma unroll
    for (int i = 0; i < 4; ++i)
        #pragma unroll
        for (int j = 0; j < 2; ++j)
            acc[i][j] = (f32x4){0.f, 0.f, 0.f, 0.f};

    const unsigned short* Arow = A + (size_t)(bm + wr + l15) * K + l4 * 8;
    const float* Wcol = W + bn + wc + l15;     // + k*N later

    bf16x8 fa0[4], fa1[4];
    float fw0[16], fw1[16];                    // raw f32 W (frag0: 0..7, frag1: 8..15)

#define LOADA(F, kb) { _Pragma("unroll") for (int m4 = 0; m4 < 4; ++m4)                   \
    F[m4] = *(const bf16x8*)(Arow + (kb) + (size_t)m4 * 16 * K); }
#define LOADW(R, kb) { const float* p_ = Wcol + (size_t)((kb) + l4 * 8) * N;              \
    _Pragma("unroll") for (int e = 0; e < 8; ++e) {                                       \
        R[e] = p_[(size_t)e * N]; R[8 + e] = p_[(size_t)e * N + 16]; } }
#define CVTW(Fb, R) {                                                                     \
    uint32x4 v0_, v1_;                                                                    \
    _Pragma("unroll") for (int e = 0; e < 4; ++e) {                                       \
        v0_[e] = cvt_pk_bf16(R[2 * e], R[2 * e + 1]);                                     \
        v1_[e] = cvt_pk_bf16(R[8 + 2 * e], R[8 + 2 * e + 1]); }                           \
    Fb[0] = __builtin_bit_cast(bf16x8, v0_);                                              \
    Fb[1] = __builtin_bit_cast(bf16x8, v1_); }
#define MFMA_CL(fa_, fb_) { _Pragma("unroll") for (int m4 = 0; m4 < 4; ++m4)              \
    _Pragma("unroll") for (int n4 = 0; n4 < 2; ++n4)                                      \
        acc[m4][n4] = __builtin_amdgcn_mfma_f32_16x16x32_bf16(fa_[m4], fb_[n4], acc[m4][n4], 0, 0, 0); }

    LOADA(fa0, kb0);      LOADW(fw0, kb0);
    LOADA(fa1, kb0 + 32); LOADW(fw1, kb0 + 32);

    for (int s = 0; s < nsteps; s += 2) {
        {
            bf16x8 ac[4], bc[2];
            #pragma unroll
            for (int m4 = 0; m4 < 4; ++m4) ac[m4] = fa0[m4];
            CVTW(bc, fw0);
            if (s + 2 < nsteps) { LOADA(fa0, kb0 + (s + 2) * 32); LOADW(fw0, kb0 + (s + 2) * 32); }
            MFMA_CL(ac, bc);
        }
        {
            bf16x8 ac[4], bc[2];
            #pragma unroll
            for (int m4 = 0; m4 < 4; ++m4) ac[m4] = fa1[m4];
            CVTW(bc, fw1);
            if (s + 3 < nsteps) { LOADA(fa1, kb0 + (s + 3) * 32); LOADW(fw1, kb0 + (s + 3) * 32); }
            MFMA_CL(ac, bc);
        }
    }
#undef LOADA
#undef LOADW
#undef CVTW
#undef MFMA_CL

    #pragma unroll
    for (int m4 = 0; m4 < 4; ++m4)
        #pragma unroll
        for (int n4 = 0; n4 < 2; ++n4) {
            const int col = bn + wc + n4 * 16 + l15;
            const int row0 = bm + wr + m4 * 16 + l4 * 4;
            #pragma unroll
            for (int rg = 0; rg < 4; ++rg) {
                float v = acc[m4][n4][rg];
                const size_t oi = (size_t)(row0 + rg) * N + col;
                if (MODE == 0) {
                    ((float*)Out)[(size_t)z * M * N + oi] = v;
                } else {
                    v += bias[col];
                    if (RELU) v = fmaxf(v, 0.f);
                    if (MODE == 1) ((float*)Out)[oi] = v;
                    else           ((unsigned short*)Out)[oi] = f2bf(v);
                }
            }
        }
}

template<int RELU, int OUTBF>
__device__ void reduce_dev(const float* __restrict__ P, const float* __restrict__ bias,
                           void* __restrict__ C, int MN, int N, int S, int idx4)
{
    const int MN4 = MN >> 2;
    if (idx4 >= MN4) return;
    const float4* P4 = (const float4*)P;
    float4 a = P4[idx4];
    for (int zz = 1; zz < S; ++zz) {
        float4 b = P4[(size_t)zz * MN4 + idx4];
        a.x += b.x; a.y += b.y; a.z += b.z; a.w += b.w;
    }
    int n0 = (idx4 * 4) % N;
    a.x += bias[n0]; a.y += bias[n0 + 1]; a.z += bias[n0 + 2]; a.w += bias[n0 + 3];
    if (RELU) {
        a.x = fmaxf(a.x, 0.f); a.y = fmaxf(a.y, 0.f);
        a.z = fmaxf(a.z, 0.f); a.w = fmaxf(a.w, 0.f);
    }
    if (OUTBF) {
        ushort4 v = {f2bf(a.x), f2bf(a.y), f2bf(a.z), f2bf(a.w)};
        ((ushort4*)C)[idx4] = v;
    } else {
        ((float4*)C)[idx4] = a;
    }
}

// device-wide barrier: all NB blocks arrive (device-scope atomic + fences).
__device__ inline void gbar(unsigned* cnt, unsigned target)
{
    __syncthreads();
    if (threadIdx.x == 0) {
        __threadfence();                        // release my writes device-wide
        atomicAdd(cnt, 1u);                     // device-scope by default
        while (__hip_atomic_load(cnt, __ATOMIC_ACQUIRE, __HIP_MEMORY_SCOPE_AGENT) < target)
            __builtin_amdgcn_s_sleep(2);
        __threadfence();                        // acquire others' writes
    }
    __syncthreads();
}

// ---------------------------------------------------- fused dense stack -----
// 512 blocks, zero LDS; __launch_bounds__(256,2) guarantees 2 blocks/CU ->
// all 512 co-resident -> the spin barrier cannot deadlock.
__global__ __launch_bounds__(256, 2)
void dense_mega(const unsigned short* __restrict__ fr,
                const float* Ws1, const float* bs1, const float* Ws2, const float* bs2,
                const float* Wn1, const float* bn1, const float* Wn2, const float* bn2,
                const float* Wn3, const float* bn3,
                unsigned short* t1, unsigned short* spec, unsigned short* h1,
                unsigned short* h2, unsigned short* ph, float* part, unsigned* sync)
{
    const int id = blockIdx.x;
    const int gid = id * 256 + threadIdx.x;
    const unsigned NB = 512;

    // L1: 256 tiles (z=16, XCD-pinned pairs)
    if (id < 256) gemm_dev<0, 0, 1>(fr, Ws1, part, nullptr, 256, 512, 12288, 768, 8, 16, id);
    gbar(sync, 1 * NB);
    reduce_dev<1, 1>(part, bs1, t1, 131072, 512, 16, gid);
    gbar(sync, 2 * NB);
    // L2: 384 tiles
    if (id < 384) gemm_dev<2, 0, 0>(t1, Ws2, spec, bs2, 256, 12288, 512, 512, 192, 1, id);
    gbar(sync, 3 * NB);
    // L3
    if (id < 256) gemm_dev<0, 0, 1>(spec, Wn1, part, nullptr, 256, 512, 12288, 768, 8, 16, id);
    gbar(sync, 4 * NB);
    reduce_dev<1, 1>(part, bn1, h1, 131072, 512, 16, gid);
    gbar(sync, 5 * NB);
    // L4: 128 tiles (z=8)
    if (id < 128) gemm_dev<0, 0, 1>(h1, Wn2, part, nullptr, 256, 512, 512, 64, 8, 8, id);
    gbar(sync, 6 * NB);
    reduce_dev<1, 1>(part, bn2, h2, 131072, 512, 8, gid);
    gbar(sync, 7 * NB);
    // L5: 384 tiles
    if (id < 384) gemm_dev<2, 0, 0>(h2, Wn3, ph, bn3, 256, 12288, 512, 512, 192, 1, id);
}

// ---------------------------------------------------------------- launch ----
extern "C" void kernel_launch(void* const* d_in, const int* in_sizes, int n_in,
                              void* d_out, int out_size, void* d_ws, size_t ws_size,
                              hipStream_t stream)
{
    const float* x   = (const float*)d_in[0];
    const float* Ws1 = (const float*)d_in[1];
    const float* bs1 = (const float*)d_in[2];
    const float* Ws2 = (const float*)d_in[3];
    const float* bs2 = (const float*)d_in[4];
    const float* Wn1 = (const float*)d_in[5];
    const float* bn1 = (const float*)d_in[6];
    const float* Wn2 = (const float*)d_in[7];
    const float* bn2 = (const float*)d_in[8];
    const float* Wn3 = (const float*)d_in[9];
    const float* bn3 = (const float*)d_in[10];
    float* out = (float*)d_out;

    char* p = (char*)d_ws;
    auto alloc = [&](size_t bytes) { char* q = p; p += (bytes + 255) & ~(size_t)255; return q; };
    unsigned short* Tch = (unsigned short*)alloc(8192);
    unsigned short* Tsh = (unsigned short*)alloc(8192);
    unsigned short* Bth = (unsigned short*)alloc((size_t)NBAND * 512 * 2);
    unsigned*       syn = (unsigned*)alloc(256);
    unsigned short* fhb = (unsigned short*)alloc((size_t)(1024 + NTOT) * 2);
    unsigned short* fr   = (unsigned short*)alloc((size_t)NTOT * 2);
    unsigned short* spec = (unsigned short*)alloc((size_t)NTOT * 2);
    unsigned short* ph   = (unsigned short*)alloc((size_t)NTOT * 2);
    unsigned short* t1   = (unsigned short*)alloc(262144);
    unsigned short* h1   = (unsigned short*)alloc(262144);
    unsigned short* h2   = (unsigned short*)alloc(262144);
    float* part          = (float*)alloc((size_t)16 * 131072 * 4);

    hipMemsetAsync(syn, 0, 256, stream);

    gen_tables<<<8, 1024, 0, stream>>>(Tch, Tsh, Bth, fhb);

    // forward fft2 real part -> bf16 f (offset 1024, zero prefix)
    dft_mfma<0><<<NIMG, 256, 0, stream>>>(x, Tch, Tsh, fhb + 1024);

    // GL fractional conv (banded block-GEMM, LDS-staged A) -> fr (bf16)
    conv_mfma<<<NTOT / 4096, 256, 0, stream>>>(fhb + 1024, Bth, fr);

    // fused dense stack: L1+red+L2+L3+red+L4+red+L5, 7 device barriers
    dense_mega<<<512, 256, 0, stream>>>(fr, Ws1, bs1, Ws2, bs2, Wn1, bn1,
                                        Wn2, bn2, Wn3, bn3,
                                        t1, spec, h1, h2, ph, part, syn);

    // inverse fft2 real part (bf16 in, f32 out, scale 1/4096)
    dft_mfma<1><<<NIMG, 256, 0, stream>>>(ph, Tch, Tsh, out);
}

// Round 18
// 136.249 us; speedup vs baseline: 5.3163x; 5.3163x over previous
//
#include <hip/hip_runtime.h>
#include <hip/hip_bf16.h>

#define NTOT 3145728   // 256*3*64*64
#define NIMG 768       // 256*3
#define CTAPS 1024     // GL conv truncation
#define NBAND 66       // conv bands: d = -1 .. 64

typedef __attribute__((ext_vector_type(8)))  short bf16x8;
typedef __attribute__((ext_vector_type(4)))  short bf16x4;
typedef __attribute__((ext_vector_type(8)))  unsigned short u16x8;
typedef __attribute__((ext_vector_type(4)))  unsigned short u16x4;
typedef __attribute__((ext_vector_type(4)))  unsigned uint32x4;
typedef __attribute__((ext_vector_type(4)))  float f32x4;
typedef __attribute__((ext_vector_type(16))) float f32x16;

__device__ inline unsigned short f2bf(float x) {
    unsigned u = __builtin_bit_cast(unsigned, x);
    u += 0x7fffu + ((u >> 16) & 1u);
    return (unsigned short)(u >> 16);
}
__device__ inline float bf2f(unsigned short u) {
    return __builtin_bit_cast(float, (unsigned)u << 16);
}
__device__ inline void split2(float v, unsigned short& hi, unsigned short& lo) {
    hi = f2bf(v);
    lo = f2bf(v - bf2f(hi));
}
// HW packed RNE convert: low16 <- bf16(a), high16 <- bf16(b). Same RNE as f2bf.
__device__ inline unsigned cvt_pk_bf16(float a, float b) {
    unsigned r;
    asm("v_cvt_pk_bf16_f32 %0, %1, %2" : "=v"(r) : "v"(a), "v"(b));
    return r;
}
__device__ inline bf16x8 ld2(const unsigned short* p) {   // 8B-aligned LDS read
    bf16x4 a = *(const bf16x4*)p;
    bf16x4 b = *(const bf16x4*)(p + 4);
    bf16x8 r;
    #pragma unroll
    for (int i = 0; i < 4; ++i) { r[i] = a[i]; r[4 + i] = b[i]; }
    return r;
}

// ---------------------------------------------------------------- tables ----
__global__ __launch_bounds__(1024)
void gen_tables(unsigned short* __restrict__ Tch, unsigned short* __restrict__ Tsh,
                unsigned short* __restrict__ Bth, unsigned short* __restrict__ fph)
{
    __shared__ float wsm[CTAPS];
    const int tid = threadIdx.x;
    const int bid = blockIdx.x;
    const float step = 6.28318530717958647692f / 64.0f;
    if (tid < 512) {
        int i = bid * 512 + tid;
        int p = i >> 6, q = i & 63;
        float ang = (float)((p * q) & 63) * step;
        Tch[i] = f2bf(cosf(ang));
        Tsh[i] = f2bf(sinf(ang));
    }
    if (bid == 0) fph[tid] = 0;                // 1024-element zero prefix
    if (tid < 64) {
        const int l = tid;
        float vals[16];
        float local = 1.0f;
        #pragma unroll
        for (int m = 0; m < 16; ++m) {
            int j = 16 * l + 1 + m;
            local *= ((float)j - 1.5f) / (float)j;
            vals[m] = local;
        }
        float scan = local;
        #pragma unroll
        for (int d = 1; d < 64; d <<= 1) {
            float o = __shfl_up(scan, (unsigned)d, 64);
            if (l >= d) scan *= o;
        }
        float prefix = __shfl_up(scan, 1u, 64);
        if (l == 0) prefix = 1.0f;
        const float s = sqrtf((float)(NTOT - 1));
        if (l == 0) wsm[0] = s;
        #pragma unroll
        for (int m = 0; m < 16; ++m) {
            int j = 16 * l + 1 + m;
            if (j < CTAPS) wsm[j] = prefix * vals[m] * s;
        }
    }
    __syncthreads();
    const int i0 = bid * 4224;                 // 66*512/8 = 4224 per block
    for (int i = i0 + tid; i < i0 + 4224; i += 1024) {
        int d = (i >> 9) - 1, o = (i >> 4) & 31, u = i & 15;
        int j = 16 * d + o - u;
        Bth[i] = (j >= 0 && j < CTAPS) ? f2bf(wsm[j]) : (unsigned short)0;
    }
}

// ---------------------------------------------------------- MFMA 2-D DFT ---
// Single-chain: bf16 data x bf16 tables, f32 accum. Fwd and inverse are
// structurally identical; template differs only at load/store.
template<int INV>
__global__ __launch_bounds__(256)
void dft_mfma(const void* __restrict__ Xin,
              const unsigned short* __restrict__ Tch, const unsigned short* __restrict__ Tsh,
              void* __restrict__ Out)
{
    __shared__ __align__(16) unsigned short Xh[64 * 68];
    __shared__ __align__(16) unsigned short Chh[64 * 68];
    __shared__ __align__(16) unsigned short Shh[64 * 68];
    const int tid = threadIdx.x;
    const int img = blockIdx.x;
    {
        const int rr = tid >> 2, c0 = (tid & 3) * 16;
        const int lb = rr * 68 + c0;
        if constexpr (!INV) {
            const float* Xf = (const float*)Xin + (size_t)img * 4096 + rr * 64 + c0;
            #pragma unroll
            for (int i = 0; i < 4; ++i) {
                float4 v = *(const float4*)(Xf + 4 * i);
                ushort4 u = {f2bf(v.x), f2bf(v.y), f2bf(v.z), f2bf(v.w)};
                *(ushort4*)&Xh[lb + 4 * i] = u;
            }
        } else {
            const unsigned short* Ph = (const unsigned short*)Xin + (size_t)img * 4096 + rr * 64 + c0;
            #pragma unroll
            for (int i = 0; i < 4; ++i)
                *(ushort4*)&Xh[lb + 4 * i] = *(const ushort4*)(Ph + 4 * i);
        }
    }
    __syncthreads();

    const int lane = tid & 63, wv = tid >> 6;
    const int r = lane & 31, g = lane >> 5;
    const int q0 = (wv >> 1) * 32, r0 = (wv & 1) * 32;
    const int tA = (q0 + r) * 64;     // T row base (A operand)
    const int xB = (r0 + r) * 68;     // X / C / S row base (B operand)

    f32x16 a1, b1;
    #pragma unroll
    for (int i = 0; i < 16; ++i) { a1[i] = 0.f; b1[i] = 0.f; }
    // ---- row pass: cos and sin chains together (independent accumulators)
    #pragma unroll
    for (int ks = 0; ks < 4; ++ks) {
        const int ko = ks * 16 + 8 * g;
        bf16x8 xh = ld2(&Xh[xB + ko]);
        bf16x8 tc = *(const bf16x8*)&Tch[tA + ko];
        bf16x8 ts = *(const bf16x8*)&Tsh[tA + ko];
        a1 = __builtin_amdgcn_mfma_f32_32x32x16_bf16(tc, xh, a1, 0, 0, 0);
        b1 = __builtin_amdgcn_mfma_f32_32x32x16_bf16(ts, xh, b1, 0, 0, 0);
    }
    #pragma unroll
    for (int reg = 0; reg < 16; ++reg) {
        int qq = q0 + (reg & 3) + 8 * (reg >> 2) + 4 * g;
        Chh[qq * 68 + r0 + r] = f2bf(a1[reg]);
        Shh[qq * 68 + r0 + r] = f2bf(-b1[reg]);
    }
    __syncthreads();

    // ---- col pass
    #pragma unroll
    for (int i = 0; i < 16; ++i) a1[i] = 0.f;
    #pragma unroll
    for (int ks = 0; ks < 4; ++ks) {
        const int ko = ks * 16 + 8 * g;
        bf16x8 ch = ld2(&Chh[xB + ko]);
        bf16x8 tc = *(const bf16x8*)&Tch[tA + ko];
        a1 = __builtin_amdgcn_mfma_f32_32x32x16_bf16(tc, ch, a1, 0, 0, 0);
        bf16x8 sh = ld2(&Shh[xB + ko]);
        bf16x8 ts = *(const bf16x8*)&Tsh[tA + ko];
        a1 = __builtin_amdgcn_mfma_f32_32x32x16_bf16(ts, sh, a1, 0, 0, 0);
    }
    #pragma unroll
    for (int reg = 0; reg < 16; ++reg) {
        int pp = q0 + (reg & 3) + 8 * (reg >> 2) + 4 * g;
        size_t oi = (size_t)img * 4096 + (size_t)pp * 64 + r0 + r;
        if constexpr (INV)
            ((float*)Out)[oi] = a1[reg] * (1.0f / 4096.0f);
        else
            ((unsigned short*)Out)[oi] = f2bf(a1[reg]);
    }
}

// ----------------------------------------------------------- MFMA conv -----
// Single chain: fr = f_bf16 (x) w_bf16, f32 accum. 66 MFMA/wave.
__global__ __launch_bounds__(256)
void conv_mfma(const unsigned short* __restrict__ fh,
               const unsigned short* __restrict__ Bth,
               unsigned short* __restrict__ fr)
{
    __shared__ __align__(16) unsigned short Ah[5120];
    const int tid = threadIdx.x;
    const size_t tb0 = (size_t)blockIdx.x * 4096;
    {
        const unsigned short* sh = fh + tb0 - 1024;   // zero prefix covers block 0
        for (int gg = tid; gg < 640; gg += 256) {
            int off = (gg ^ ((gg >> 3) & 7)) << 3;    // swizzled element offset
            *(bf16x8*)&Ah[off] = *(const bf16x8*)(sh + gg * 8);
        }
    }
    __syncthreads();

    const int lane = tid & 63;
    const int wv = tid >> 6;
    const int r = lane & 31, g = lane >> 5;
    const int bo = 16 * r + 8 * g;
    const int base_gg = 128 * (wv + 1) + 4 * r + g + 2;   // A-frag group at dd=0

    f32x16 a1;
    #pragma unroll
    for (int i = 0; i < 16; ++i) a1[i] = 0.f;

    const unsigned short* bhp = Bth + bo;
    bf16x8 bh0 = *(const bf16x8*)(bhp);
    bf16x8 bh1 = *(const bf16x8*)(bhp + 512);

    for (int dd = 0; dd < NBAND; dd += 2) {
        bf16x8 nh0, nh1;
        if (dd + 2 < NBAND) {
            nh0 = *(const bf16x8*)(bhp + 512 * (dd + 2));
            nh1 = *(const bf16x8*)(bhp + 512 * (dd + 3));
        }
        {
            int gg = base_gg - 2 * dd;
            int off = (gg ^ ((gg >> 3) & 7)) << 3;
            bf16x8 avh = *(const bf16x8*)&Ah[off];
            a1 = __builtin_amdgcn_mfma_f32_32x32x16_bf16(avh, bh0, a1, 0, 0, 0);
        }
        {
            int gg = base_gg - 2 * (dd + 1);
            int off = (gg ^ ((gg >> 3) & 7)) << 3;
            bf16x8 avh = *(const bf16x8*)&Ah[off];
            a1 = __builtin_amdgcn_mfma_f32_32x32x16_bf16(avh, bh1, a1, 0, 0, 0);
        }
        bh0 = nh0; bh1 = nh1;
    }

    const size_t tb = tb0 + 1024 * wv;
    #pragma unroll
    for (int reg = 0; reg < 16; ++reg) {
        int row = (reg & 3) + 8 * (reg >> 2) + 4 * g;
        fr[tb + 32 * row + r] = f2bf(a1[reg]);
    }
}

// -------------------------------------------------- no-barrier MFMA GEMM ----
// D = A(bf16) @ W(f32 direct, cvt_pk in-register). 128x64 tile, 4 waves,
// BK=32, no LDS, no in-loop barriers, 2-deep named-register prefetch.
// XMAP=0 (L2/L5): old decode; the 2 bm-tiles of a W panel are ids 8 apart.
// XMAP=1 (L1/L3/L4, split-K): each (bm,z) pair pinned to XCD p%8.
template<int MODE, int RELU, int XMAP>
__global__ __launch_bounds__(256)
void gemm_nb(const unsigned short* __restrict__ A, const float* __restrict__ W,
             void* __restrict__ Out, const float* __restrict__ bias,
             int M, int N, int K, int kChunk, int nbn, int nz,
             unsigned short* __restrict__ Out2)
{
    const int tid = threadIdx.x;
    const int id = blockIdx.x;
    int bm, bn, z;
    if (XMAP == 0) {
        const int gq = id >> 4, rr = id & 15;      // GRP = 16
        const int t  = gq * 8 + (rr & 7);
        bm = (rr >> 3) * 128;
        bn = (t % nbn) * 64;
        z  = t / nbn;
    } else {
        const int x = id & 7, j = id >> 3;
        const int p = x + 8 * (j / nbn);           // (bm,z) pair, pinned to XCD x
        bn = (j % nbn) * 64;
        bm = (p / nz) * 128;
        z  = p % nz;
    }
    const int kb0 = z * kChunk;
    const int nsteps = kChunk >> 5;            // must be EVEN

    const int lane = tid & 63, wv = tid >> 6;
    const int wr = (wv >> 1) * 64, wc = (wv & 1) * 32;
    const int l15 = lane & 15, l4 = lane >> 4;

    f32x4 acc[4][2];
    #pragma unroll
    for (int i = 0; i < 4; ++i)
        #pragma unroll
        for (int j = 0; j < 2; ++j)
            acc[i][j] = (f32x4){0.f, 0.f, 0.f, 0.f};

    const unsigned short* Arow = A + (size_t)(bm + wr + l15) * K + l4 * 8;
    const float* Wcol = W + bn + wc + l15;     // + k*N later

    bf16x8 fa0[4], fa1[4];
    float fw0[16], fw1[16];                    // raw f32 W (frag0: 0..7, frag1: 8..15)

#define LOADA(F, kb) { _Pragma("unroll") for (int m4 = 0; m4 < 4; ++m4)                   \
    F[m4] = *(const bf16x8*)(Arow + (kb) + (size_t)m4 * 16 * K); }
#define LOADW(R, kb) { const float* p_ = Wcol + (size_t)((kb) + l4 * 8) * N;              \
    _Pragma("unroll") for (int e = 0; e < 8; ++e) {                                       \
        R[e] = p_[(size_t)e * N]; R[8 + e] = p_[(size_t)e * N + 16]; } }
#define CVTW(Fb, R) {                                                                     \
    uint32x4 v0_, v1_;                                                                    \
    _Pragma("unroll") for (int e = 0; e < 4; ++e) {                                       \
        v0_[e] = cvt_pk_bf16(R[2 * e], R[2 * e + 1]);                                     \
        v1_[e] = cvt_pk_bf16(R[8 + 2 * e], R[8 + 2 * e + 1]); }                           \
    Fb[0] = __builtin_bit_cast(bf16x8, v0_);                                              \
    Fb[1] = __builtin_bit_cast(bf16x8, v1_); }
#define MFMA_CL(fa_, fb_) { _Pragma("unroll") for (int m4 = 0; m4 < 4; ++m4)              \
    _Pragma("unroll") for (int n4 = 0; n4 < 2; ++n4)                                      \
        acc[m4][n4] = __builtin_amdgcn_mfma_f32_16x16x32_bf16(fa_[m4], fb_[n4], acc[m4][n4], 0, 0, 0); }

    LOADA(fa0, kb0);      LOADW(fw0, kb0);
    LOADA(fa1, kb0 + 32); LOADW(fw1, kb0 + 32);

    for (int s = 0; s < nsteps; s += 2) {
        {
            bf16x8 ac[4], bc[2];
            #pragma unroll
            for (int m4 = 0; m4 < 4; ++m4) ac[m4] = fa0[m4];
            CVTW(bc, fw0);
            if (s + 2 < nsteps) { LOADA(fa0, kb0 + (s + 2) * 32); LOADW(fw0, kb0 + (s + 2) * 32); }
            MFMA_CL(ac, bc);
        }
        {
            bf16x8 ac[4], bc[2];
            #pragma unroll
            for (int m4 = 0; m4 < 4; ++m4) ac[m4] = fa1[m4];
            CVTW(bc, fw1);
            if (s + 3 < nsteps) { LOADA(fa1, kb0 + (s + 3) * 32); LOADW(fw1, kb0 + (s + 3) * 32); }
            MFMA_CL(ac, bc);
        }
    }
#undef LOADA
#undef LOADW
#undef CVTW
#undef MFMA_CL

    #pragma unroll
    for (int m4 = 0; m4 < 4; ++m4)
        #pragma unroll
        for (int n4 = 0; n4 < 2; ++n4) {
            const int col = bn + wc + n4 * 16 + l15;
            const int row0 = bm + wr + m4 * 16 + l4 * 4;
            #pragma unroll
            for (int rg = 0; rg < 4; ++rg) {
                float v = acc[m4][n4][rg];
                const size_t oi = (size_t)(row0 + rg) * N + col;
                if (MODE == 0) {
                    ((float*)Out)[(size_t)z * M * N + oi] = v;
                } else {
                    v += bias[col];
                    if (RELU) v = fmaxf(v, 0.f);
                    if (MODE == 1) {
                        ((float*)Out)[oi] = v;
                    } else if (MODE == 2) {
                        ((unsigned short*)Out)[oi] = f2bf(v);
                    } else {
                        unsigned short h, l; split2(v, h, l);
                        ((unsigned short*)Out)[oi] = h; Out2[oi] = l;
                    }
                }
            }
        }
}

// --------------------------------------------------------------- reduce -----
template<int RELU, int OUTBF>
__global__ __launch_bounds__(256)
void reduce_bias(const float* __restrict__ P, const float* __restrict__ bias,
                 void* __restrict__ C, int MN, int N, int S)
{
    const int idx4 = blockIdx.x * 256 + threadIdx.x;
    const int MN4 = MN >> 2;
    if (idx4 >= MN4) return;
    const float4* P4 = (const float4*)P;
    float4 a = P4[idx4];
    for (int zz = 1; zz < S; ++zz) {
        float4 b = P4[(size_t)zz * MN4 + idx4];
        a.x += b.x; a.y += b.y; a.z += b.z; a.w += b.w;
    }
    int n0 = (idx4 * 4) % N;
    a.x += bias[n0]; a.y += bias[n0 + 1]; a.z += bias[n0 + 2]; a.w += bias[n0 + 3];
    if (RELU) {
        a.x = fmaxf(a.x, 0.f); a.y = fmaxf(a.y, 0.f);
        a.z = fmaxf(a.z, 0.f); a.w = fmaxf(a.w, 0.f);
    }
    if (OUTBF) {
        ushort4 v = {f2bf(a.x), f2bf(a.y), f2bf(a.z), f2bf(a.w)};
        ((ushort4*)C)[idx4] = v;
    } else {
        ((float4*)C)[idx4] = a;
    }
}

// ---------------------------------------------------------------- launch ----
extern "C" void kernel_launch(void* const* d_in, const int* in_sizes, int n_in,
                              void* d_out, int out_size, void* d_ws, size_t ws_size,
                              hipStream_t stream)
{
    const float* x   = (const float*)d_in[0];
    const float* Ws1 = (const float*)d_in[1];
    const float* bs1 = (const float*)d_in[2];
    const float* Ws2 = (const float*)d_in[3];
    const float* bs2 = (const float*)d_in[4];
    const float* Wn1 = (const float*)d_in[5];
    const float* bn1 = (const float*)d_in[6];
    const float* Wn2 = (const float*)d_in[7];
    const float* bn2 = (const float*)d_in[8];
    const float* Wn3 = (const float*)d_in[9];
    const float* bn3 = (const float*)d_in[10];
    float* out = (float*)d_out;

    char* p = (char*)d_ws;
    auto alloc = [&](size_t bytes) { char* q = p; p += (bytes + 255) & ~(size_t)255; return q; };
    unsigned short* Tch = (unsigned short*)alloc(8192);
    unsigned short* Tsh = (unsigned short*)alloc(8192);
    unsigned short* Bth = (unsigned short*)alloc((size_t)NBAND * 512 * 2);
    unsigned short* fhb = (unsigned short*)alloc((size_t)(1024 + NTOT) * 2);
    unsigned short* fr   = (unsigned short*)alloc((size_t)NTOT * 2);
    unsigned short* spec = (unsigned short*)alloc((size_t)NTOT * 2);
    unsigned short* ph   = (unsigned short*)alloc((size_t)NTOT * 2);
    unsigned short* t1   = (unsigned short*)alloc(262144);
    unsigned short* h1   = (unsigned short*)alloc(262144);
    unsigned short* h2   = (unsigned short*)alloc(262144);
    float* part          = (float*)alloc((size_t)16 * 131072 * 4);

    gen_tables<<<8, 1024, 0, stream>>>(Tch, Tsh, Bth, fhb);

    // forward fft2 real part -> bf16 f (offset 1024, zero prefix)
    dft_mfma<0><<<NIMG, 256, 0, stream>>>(x, Tch, Tsh, fhb + 1024);

    // GL fractional conv (banded block-GEMM, LDS-staged A) -> fr (bf16)
    conv_mfma<<<NTOT / 4096, 256, 0, stream>>>(fhb + 1024, Bth, fr);

    // spectral_operator: L1 (z=16, XCD-pinned pairs) + reduce, L2
    gemm_nb<0, 0, 1><<<256, 256, 0, stream>>>(fr, Ws1, part, nullptr,
                                              256, 512, 12288, 768, 8, 16, nullptr);
    reduce_bias<1, 1><<<128, 256, 0, stream>>>(part, bs1, t1, 131072, 512, 16);
    gemm_nb<2, 0, 0><<<384, 256, 0, stream>>>(t1, Ws2, spec, bs2,
                                              256, 12288, 512, 512, 192, 1, nullptr);

    // neural_operator: L3 (XCD-pinned), L4 (XCD-pinned), L5 (bf16 single out)
    gemm_nb<0, 0, 1><<<256, 256, 0, stream>>>(spec, Wn1, part, nullptr,
                                              256, 512, 12288, 768, 8, 16, nullptr);
    reduce_bias<1, 1><<<128, 256, 0, stream>>>(part, bn1, h1, 131072, 512, 16);
    gemm_nb<0, 0, 1><<<128, 256, 0, stream>>>(h1, Wn2, part, nullptr,
                                              256, 512, 512, 64, 8, 8, nullptr);
    reduce_bias<1, 1><<<128, 256, 0, stream>>>(part, bn2, h2, 131072, 512, 8);
    gemm_nb<2, 0, 0><<<384, 256, 0, stream>>>(h2, Wn3, ph, bn3,
                                              256, 12288, 512, 512, 192, 1, nullptr);

    // inverse fft2 real part (bf16 in, f32 out, scale 1/4096)
    dft_mfma<1><<<NIMG, 256, 0, stream>>>(ph, Tch, Tsh, out);
}